// Round 1
// baseline (1182.388 us; speedup 1.0000x reference)
//
#include <hip/hip_runtime.h>
#include <math.h>

#define N_  100000
#define P_  96
#define V_  4
#define M_  70000
#define K_  43
#define KC_ 27

typedef unsigned short u16;
typedef __attribute__((ext_vector_type(8))) short bf16x8;
typedef __attribute__((ext_vector_type(4))) float f32x4;
typedef __attribute__((ext_vector_type(16))) float f32x16;

__device__ __forceinline__ u16 f2bf(float f) {
    unsigned int u = __float_as_uint(f);
    u += 0x7fffu + ((u >> 16) & 1u);   // round-to-nearest-even
    return (u16)(u >> 16);
}
__device__ __forceinline__ float bf2f(u16 h) {
    return __uint_as_float(((unsigned int)h) << 16);
}

// async global->LDS DMA, 16 B per lane; dest = wave-uniform base + lane*16
__device__ __forceinline__ void gl_lds16(const u16* g, u16* l) {
    __builtin_amdgcn_global_load_lds(
        (const __attribute__((address_space(1))) void*)g,
        (__attribute__((address_space(3))) void*)l, 16, 0, 0);
}

// ---------------------------------------------------------------------------
__global__ __launch_bounds__(256) void k_build_srcof(const int* __restrict__ km,
                                                     int* __restrict__ srcOf) {
    int idx = blockIdx.x * 256 + threadIdx.x;
    if (idx >= K_ * M_) return;
    int k = idx / M_;
    int e = idx - k * M_;
    const int* p = km + (size_t)(k * M_ + e) * 2;
    srcOf[(size_t)k * N_ + p[1]] = p[0];
}

// rowAbs[r] = sum_j |x[r][j]|  AND  xb = bf16(x) at LINE-ALIGNED stride 128 u16
// (256 B rows: each row = exactly two 128B cache lines for the gather)
__global__ __launch_bounds__(256) void k_rowabs_cvt(const float* __restrict__ x,
                                                    float* __restrict__ rowAbs,
                                                    u16* __restrict__ xb) {
    int row = blockIdx.x * 4 + (threadIdx.x >> 6);
    int lane = threadIdx.x & 63;
    if (row >= N_) return;
    const float* xr = x + (size_t)row * 96;
    float s = 0.f;
    for (int j = lane; j < 96; j += 64) {
        float v = xr[j];
        s += fabsf(v);
        xb[(size_t)row * 128 + j] = f2bf(v);   // pad bytes never read
    }
#pragma unroll
    for (int o = 32; o > 0; o >>= 1) s += __shfl_down(s, o, 64);
    if (lane == 0) rowAbs[row] = s;
}

// Padded weight image for async staging: Wp[k*10240 + n*104 + j] = bf16(W[k][j][n])
__global__ __launch_bounds__(256) void k_wt96p(const float* __restrict__ W,
                                               u16* __restrict__ Wp) {
    int idx = blockIdx.x * 256 + threadIdx.x;
    if (idx >= KC_ * 96 * 96) return;
    int k = idx / 9216, rem = idx - k * 9216, n = rem / 96, j = rem - n * 96;
    Wp[(size_t)k * 10240 + n * 104 + j] = f2bf(W[(size_t)k * 9216 + j * 96 + n]);
}

// Wt4[k][n][j] = bf16(W[k][j][n]) for n<4 else 0   (27 x 16 x 96)
__global__ __launch_bounds__(256) void k_wt4(const float* __restrict__ W,
                                             u16* __restrict__ Wt) {
    int idx = blockIdx.x * 256 + threadIdx.x;
    if (idx >= KC_ * 16 * 96) return;
    int k = idx / 1536, rem = idx - k * 1536, n = rem / 96, j = rem - n * 96;
    Wt[idx] = (n < 4) ? f2bf(W[(size_t)k * 384 + j * 4 + n]) : (u16)0;
}

// w1b[j][c32] = bf16(W1[c][j]) c<4 else 0; w2b[n16][j] = bf16(W2[j][n]) n<4 else 0
__global__ __launch_bounds__(256) void k_w12b(const float* __restrict__ W1,
                                              const float* __restrict__ W2,
                                              u16* __restrict__ w1b,
                                              u16* __restrict__ w2b) {
    int t = blockIdx.x * 256 + threadIdx.x;
    if (t < 96 * 32) {
        int j = t >> 5, c = t & 31;
        w1b[t] = (c < 4) ? f2bf(W1[c * 96 + j]) : (u16)0;
    }
    if (t < 16 * 96) {
        int n = t / 96, j = t - n * 96;
        w2b[t] = (n < 4) ? f2bf(W2[j * 4 + n]) : (u16)0;
    }
}

// ---------------------------------------------------------------------------
// Dual conv, 32x32x16 MFMA, 192 rows/block, 384 threads (6 waves).
// A-gather: 16 lanes/row x 16B from 256B-aligned padded rows -> each wave
// instruction covers 4 consecutive rows, touching every needed 128B line
// exactly once (2 line-transactions/row vs ~10 in the chunk-pair scheme).
// B staged async via global_load_lds; BN stats fused in epilogue.
__global__ __launch_bounds__(384, 3) void k_conv96_dual(
    const u16* __restrict__ xb, const u16* __restrict__ Wqp,
    const u16* __restrict__ Wvp, const int* __restrict__ srcOf,
    u16* __restrict__ yQ, u16* __restrict__ yV,
    float* __restrict__ statsQ, float* __restrict__ statsV) {
    __shared__ u16 sA[192 * 104];   // 39,936 B
    __shared__ u16 sBq[10240];      // 20,480 B (96x104 padded image)
    __shared__ u16 sBv[10240];      // 20,480 B
    const int r0 = blockIdx.x * 192;
    const int t = threadIdx.x;
    const int wv = t / 64, lane = t & 63;
    const int n32 = lane & 31, half = lane >> 5;
    const int gc = t & 15;          // gather chunk (16B units), 12 valid
    const int grb = t >> 4;         // gather row base 0..23
    f32x16 accq[3], accv[3];
#pragma unroll
    for (int i = 0; i < 3; i++) {
#pragma unroll
        for (int j = 0; j < 16; j++) { accq[i][j] = 0.f; accv[i][j] = 0.f; }
    }

    for (int k = 0; k < KC_; k++) {
        __syncthreads();
        // --- B: async DMA, 40 wave-issues of 1 KB split across 6 waves
        {
            const u16* gq = Wqp + (size_t)k * 10240;
            const u16* gv = Wvp + (size_t)k * 10240;
            for (int i = wv; i < 40; i += 6) {
                int mv = (i >= 20);
                int off = (mv ? i - 20 : i) * 512 + lane * 8;
                gl_lds16((mv ? gv : gq) + off, (mv ? (u16*)sBv : (u16*)sBq) + off);
            }
        }
        // --- A: gathered rows; 16 lanes/row, chunks >=12 masked (pad)
        if (gc < 12) {
            uint4 va[8];
#pragma unroll
            for (int j = 0; j < 8; j++) {
                int rL = j * 24 + grb;
                int r = r0 + rL;
                int src = (r < N_) ? srcOf[(size_t)k * N_ + r] : -1;
                va[j] = make_uint4(0, 0, 0, 0);
                if (src >= 0)
                    va[j] = *(const uint4*)(xb + (size_t)src * 128 + gc * 8);
            }
#pragma unroll
            for (int j = 0; j < 8; j++)
                *(uint4*)(sA + (j * 24 + grb) * 104 + gc * 8) = va[j];
        }
        __syncthreads();   // drains vmcnt (DMA) + lgkmcnt (ds_write)
        // --- MFMA: 6 K-steps x 3 n-tiles x 2 matrices
#pragma unroll
        for (int ks = 0; ks < 6; ks++) {
            bf16x8 af = *(const bf16x8*)(sA + (wv * 32 + n32) * 104 + ks * 16 + half * 8);
#pragma unroll
            for (int nt = 0; nt < 3; nt++) {
                bf16x8 bq = *(const bf16x8*)(sBq + (nt * 32 + n32) * 104 + ks * 16 + half * 8);
                accq[nt] = __builtin_amdgcn_mfma_f32_32x32x16_bf16(af, bq, accq[nt], 0, 0, 0);
                bf16x8 bv = *(const bf16x8*)(sBv + (nt * 32 + n32) * 104 + ks * 16 + half * 8);
                accv[nt] = __builtin_amdgcn_mfma_f32_32x32x16_bf16(af, bv, accv[nt], 0, 0, 0);
            }
        }
    }
    // --- outputs (bf16); C/D: col=lane&31, row=(reg&3)+8*(reg>>2)+4*half
#pragma unroll
    for (int nt = 0; nt < 3; nt++) {
#pragma unroll
        for (int reg = 0; reg < 16; reg++) {
            int row = (reg & 3) + 8 * (reg >> 2) + 4 * half;
            int r = r0 + wv * 32 + row;
            if (r < N_) {
                yQ[(size_t)r * 96 + nt * 32 + n32] = f2bf(accq[nt][reg]);
                yV[(size_t)r * 96 + nt * 32 + n32] = f2bf(accv[nt][reg]);
            }
        }
    }
    // --- fused BN stats (invalid rows contribute exact zeros)
    __syncthreads();
    float* sred = (float*)sA;   // 6 waves x 192 floats
    for (int pass = 0; pass < 2; pass++) {
        f32x16* acc = pass ? accv : accq;
        float* st = pass ? statsV : statsQ;
#pragma unroll
        for (int nt = 0; nt < 3; nt++) {
            float sv = 0.f, qv = 0.f;
#pragma unroll
            for (int reg = 0; reg < 16; reg++) {
                float a = acc[nt][reg];
                sv += a; qv += a * a;
            }
            sv += __shfl_xor(sv, 32, 64);
            qv += __shfl_xor(qv, 32, 64);
            if (half == 0) {
                sred[wv * 192 + nt * 32 + n32] = sv;
                sred[wv * 192 + 96 + nt * 32 + n32] = qv;
            }
        }
        __syncthreads();
        if (t < 192) {
            float tot = 0.f;
#pragma unroll
            for (int w = 0; w < 6; w++) tot += sred[w * 192 + t];
            atomicAdd(&st[t], tot);
        }
        __syncthreads();
    }
}

// 96->4 conv via MFMA (N padded to 16). 128 rows/block; same line-aligned gather.
__global__ __launch_bounds__(256) void k_conv4_mfma(
    const u16* __restrict__ xbA, const u16* __restrict__ Wt4,
    const int* __restrict__ srcOf, float* __restrict__ qf) {
    __shared__ u16 sA[128 * 104];
    __shared__ u16 sB[16 * 104];
    const int r0 = blockIdx.x * 128;
    const int t = threadIdx.x;
    const int wv = t >> 6, lane = t & 63;
    const int m = lane & 15, quad = lane >> 4;
    const int gc = t & 15;
    const int grb = t >> 4;         // 0..15
    f32x4 acc[2];
    acc[0] = (f32x4){0.f, 0.f, 0.f, 0.f};
    acc[1] = (f32x4){0.f, 0.f, 0.f, 0.f};
    for (int k = 0; k < KC_; k++) {
        __syncthreads();
        if (gc < 12) {
            uint4 va[8];
#pragma unroll
            for (int j = 0; j < 8; j++) {
                int rL = j * 16 + grb;
                int r = r0 + rL;
                int src = (r < N_) ? srcOf[(size_t)k * N_ + r] : -1;
                va[j] = make_uint4(0, 0, 0, 0);
                if (src >= 0)
                    va[j] = *(const uint4*)(xbA + (size_t)src * 128 + gc * 8);
            }
#pragma unroll
            for (int j = 0; j < 8; j++)
                *(uint4*)(sA + (j * 16 + grb) * 104 + gc * 8) = va[j];
        }
        if (t < 192) {
            int n = t / 12, jc = t - (t / 12) * 12;
            *(uint4*)(sB + n * 104 + jc * 8) =
                *(const uint4*)(Wt4 + (size_t)k * 1536 + n * 96 + jc * 8);
        }
        __syncthreads();
#pragma unroll
        for (int kk = 0; kk < 3; kk++) {
            bf16x8 bfr = *(const bf16x8*)(sB + m * 104 + kk * 32 + quad * 8);
#pragma unroll
            for (int rt = 0; rt < 2; rt++) {
                bf16x8 af = *(const bf16x8*)(sA + ((wv * 2 + rt) * 16 + m) * 104 + kk * 32 + quad * 8);
                acc[rt] = __builtin_amdgcn_mfma_f32_16x16x32_bf16(af, bfr, acc[rt], 0, 0, 0);
            }
        }
    }
    if (m < 4) {
#pragma unroll
        for (int rt = 0; rt < 2; rt++)
#pragma unroll
            for (int rg = 0; rg < 4; rg++) {
                int r = r0 + (wv * 2 + rt) * 16 + quad * 4 + rg;
                if (r < N_) qf[(size_t)r * 4 + m] = acc[rt][rg];
            }
    }
}

// ---------------------------------------------------------------------------
__global__ __launch_bounds__(192) void k_bnstats96(const float* __restrict__ xin,
                                                   float* __restrict__ stats) {
    __shared__ float sS[192], sQ[192];
    int t = threadIdx.x;
    int ch = t % 96, half = t / 96;
    float s = 0.f, q = 0.f;
    for (int r = blockIdx.x * 2 + half; r < N_; r += gridDim.x * 2) {
        float v = xin[(size_t)r * 96 + ch];
        s += v; q += v * v;
    }
    sS[t] = s; sQ[t] = q;
    __syncthreads();
    if (t < 96) {
        atomicAdd(&stats[ch], sS[t] + sS[t + 96]);
        atomicAdd(&stats[96 + ch], sQ[t] + sQ[t + 96]);
    }
}

__global__ __launch_bounds__(256) void k_bnstats4(const float* __restrict__ xin,
                                                  float* __restrict__ stats) {
    __shared__ float sS[256], sQ[256];
    int t = threadIdx.x;
    int c = t & 3, sub = t >> 2;
    float s = 0.f, q = 0.f;
    for (int r = blockIdx.x * 64 + sub; r < N_; r += gridDim.x * 64) {
        float v = xin[(size_t)r * 4 + c];
        s += v; q += v * v;
    }
    sS[t] = s; sQ[t] = q;
    __syncthreads();
    for (int off = 128; off >= 4; off >>= 1) {
        if (t < off) { sS[t] += sS[t + off]; sQ[t] += sQ[t + off]; }
        __syncthreads();
    }
    if (t < 4) {
        atomicAdd(&stats[t], sS[t]);
        atomicAdd(&stats[96 + t], sQ[t]);
    }
}

// f32 in/out (MODE 0: relu(bn)  MODE 2: relu(bn)+aux)
template <int C, int MODE>
__global__ __launch_bounds__(256) void k_bnapply(float* __restrict__ y,
                                                 const float* __restrict__ stats,
                                                 const float* __restrict__ g,
                                                 const float* __restrict__ b,
                                                 const float* __restrict__ aux) {
    int idx = blockIdx.x * 256 + threadIdx.x;
    if (idx >= N_ * C) return;
    int ch = idx % C;
    float mean = stats[ch] * (1.f / N_);
    float var = stats[96 + ch] * (1.f / N_) - mean * mean;
    float scale = g[ch] * rsqrtf(fmaxf(var, 0.f) + 1e-5f);
    float v = (y[idx] - mean) * scale + b[ch];
    v = fmaxf(v, 0.f);
    if (MODE == 2) v += aux[idx];
    y[idx] = v;
}

// bf16 in -> bf16 out, C=96, output row stride OS.
// MODE 0: relu(bn)  MODE 1: relu(bn)+pe_repeat
template <int MODE, int OS>
__global__ __launch_bounds__(256) void k_bnapply96_b2b(
    const u16* __restrict__ yin, const float* __restrict__ stats,
    const float* __restrict__ g, const float* __restrict__ b,
    const float* __restrict__ aux, u16* __restrict__ yout) {
    int idx = blockIdx.x * 256 + threadIdx.x;
    if (idx >= N_ * 96) return;
    int ch = idx % 96;
    int r = idx / 96;
    float mean = stats[ch] * (1.f / N_);
    float var = stats[96 + ch] * (1.f / N_) - mean * mean;
    float scale = g[ch] * rsqrtf(fmaxf(var, 0.f) + 1e-5f);
    float v = (bf2f(yin[idx]) - mean) * scale + b[ch];
    v = fmaxf(v, 0.f);
    if (MODE == 1) v += aux[(size_t)r * 4 + (ch / 24)];
    yout[(size_t)r * OS + ch] = f2bf(v);
}

__global__ __launch_bounds__(256) void k_pe1(const float* __restrict__ coords,
                                             const float* __restrict__ Wp1,
                                             float* __restrict__ out) {
    int idx = blockIdx.x * 256 + threadIdx.x;
    if (idx >= N_ * 96) return;
    int r = idx / 96, ch = idx - r * 96;
    float c0 = coords[r * 3], c1 = coords[r * 3 + 1], c2 = coords[r * 3 + 2];
    out[idx] = c0 * Wp1[ch] + c1 * Wp1[96 + ch] + c2 * Wp1[192 + ch];
}

__global__ __launch_bounds__(256) void k_pe2(const float* __restrict__ hin,
                                             const float* __restrict__ Wp2,
                                             float* __restrict__ out) {
    int idx = blockIdx.x * 256 + threadIdx.x;
    if (idx >= N_ * 4) return;
    int r = idx / 4, c = idx & 3;
    const float* hr = hin + (size_t)r * 96;
    float acc = 0.f;
#pragma unroll 4
    for (int j = 0; j < 96; j++) acc += hr[j] * Wp2[j * 4 + c];
    out[idx] = acc;
}

// ---------------------------------------------------------------------------
// MFMA attention logits (32 rows/block), bf16 LDS softmax state.
__global__ __launch_bounds__(256) void k_attn_logits_mfma(
    const float* __restrict__ qf, const int* __restrict__ srcOf,
    const float* __restrict__ rowAbs,
    const u16* __restrict__ w1b, const float* __restrict__ b1,
    const u16* __restrict__ w2b, const float* __restrict__ b2,
    u16* __restrict__ wb) {
    __shared__ u16 hbuf[4][16 * 104];
    __shared__ u16 slogb[32][176];
    __shared__ u16 smk16[32][44];
    const int t = threadIdx.x;
    const int wv = t >> 6, lane = t & 63;
    const int col = lane & 15, quad = lane >> 4;
    const int r0 = blockIdx.x * 32;

    bf16x8 w1f[6];
    float b1v[6];
#pragma unroll
    for (int nt = 0; nt < 6; nt++) {
        w1f[nt] = *(const bf16x8*)(w1b + (nt * 16 + col) * 32 + quad * 8);
        b1v[nt] = b1[nt * 16 + col];
    }
    bf16x8 w2f[3];
#pragma unroll
    for (int kk = 0; kk < 3; kk++)
        w2f[kk] = *(const bf16x8*)(w2b + col * 96 + kk * 32 + quad * 8);
    float b2v = b2[col & 3];

    u16* hb = hbuf[wv];
    for (int tt = 0; tt < 22; tt++) {
        int tileBase = (wv * 22 + tt) * 16;
        bf16x8 af = (bf16x8){0, 0, 0, 0, 0, 0, 0, 0};
        if (quad == 0) {
            int P = tileBase + col;
            int rL = P / 44, k = P - rL * 44;
            int kc = (k < 43) ? k : 42;
            int r = r0 + rL;
            int s = srcOf[(size_t)kc * N_ + r];
            if (k == 43) s = -1;
            int sc = (s >= 0) ? s : 0;
            float mk = (s >= 0 && rowAbs[sc] > 0.f) ? 1.f : 0.f;
            float4 qs = *(const float4*)(qf + (size_t)sc * 4);
            float4 qr = *(const float4*)(qf + (size_t)r * 4);
            af[0] = (short)f2bf((qs.x - qr.x) * mk);
            af[1] = (short)f2bf((qs.y - qr.y) * mk);
            af[2] = (short)f2bf((qs.z - qr.z) * mk);
            af[3] = (short)f2bf((qs.w - qr.w) * mk);
            if (k < 43) smk16[rL][k] = (u16)(mk > 0.f ? 1 : 0);
        }
        f32x4 c1[6];
#pragma unroll
        for (int nt = 0; nt < 6; nt++) {
            c1[nt] = (f32x4){0.f, 0.f, 0.f, 0.f};
            c1[nt] = __builtin_amdgcn_mfma_f32_16x16x32_bf16(af, w1f[nt], c1[nt], 0, 0, 0);
        }
#pragma unroll
        for (int nt = 0; nt < 6; nt++) {
#pragma unroll
            for (int rg = 0; rg < 4; rg++) {
                float h = fmaxf(c1[nt][rg] + b1v[nt], 0.f);
                hb[(quad * 4 + rg) * 104 + nt * 16 + col] = f2bf(h);
            }
        }
        f32x4 acc2 = (f32x4){0.f, 0.f, 0.f, 0.f};
#pragma unroll
        for (int kk = 0; kk < 3; kk++) {
            bf16x8 a2 = *(const bf16x8*)(hb + col * 104 + kk * 32 + quad * 8);
            acc2 = __builtin_amdgcn_mfma_f32_16x16x32_bf16(a2, w2f[kk], acc2, 0, 0, 0);
        }
        if (col < 4) {
#pragma unroll
            for (int rg = 0; rg < 4; rg++) {
                int P = tileBase + quad * 4 + rg;
                int rL = P / 44, k = P - rL * 44;
                if (k < 43) {
                    float mval = (float)smk16[rL][k];
                    slogb[rL][k * 4 + col] = f2bf((acc2[rg] + b2v) * mval);
                }
            }
        }
    }
    __syncthreads();

    if (t < 128) {
        int rL = t >> 2, c = t & 3;
        float mx = 0.f;
        for (int k = 0; k < K_; k++) mx = fmaxf(mx, bf2f(slogb[rL][k * 4 + c]));
        float den = 0.f;
        for (int k = 0; k < K_; k++) den += __expf(bf2f(slogb[rL][k * 4 + c]) - mx);
        float inv = 1.f / den;
        for (int k = 0; k < K_; k++)
            slogb[rL][k * 4 + c] = f2bf(__expf(bf2f(slogb[rL][k * 4 + c]) - mx) * inv);
    }
    __syncthreads();

    for (int p = t; p < 32 * 43; p += 256) {
        int rL = p / 43, k = p - rL * 43;
        int idxk = (k < 27) ? k : ((k < 35) ? (k - 27) : (k - 35));
        u16 mk = smk16[rL][k];
        ushort4 wout = make_ushort4(0, 0, 0, 0);
        if (mk) {
            wout.x = slogb[rL][idxk * 4 + 0];
            wout.y = slogb[rL][idxk * 4 + 1];
            wout.z = slogb[rL][idxk * 4 + 2];
            wout.w = slogb[rL][idxk * 4 + 3];
        }
        *(ushort4*)(wb + ((size_t)(r0 + rL) * 44 + k) * 4) = wout;
    }
}

// out[r][ch] = sum_k wb[r][k][cg] * vfb[src_k[r]][ch]
__global__ __launch_bounds__(256) void k_attn_gather(
    const u16* __restrict__ vfb, const u16* __restrict__ wb,
    const int* __restrict__ srcOf, float* __restrict__ out) {
    int idx = blockIdx.x * 256 + threadIdx.x;
    int r = idx / 24, c4 = idx - r * 24;
    if (r >= N_) return;
    int cg = c4 / 6;
    const u16* wrow = wb + (size_t)r * 176 + cg;
    float a0 = 0.f, a1 = 0.f, a2 = 0.f, a3 = 0.f;
    for (int k = 0; k < K_; k++) {
        int s = srcOf[(size_t)k * N_ + r];
        float w = bf2f(wrow[(size_t)k * 4]);
        w = (s >= 0) ? w : 0.f;
        int sc = (s >= 0) ? s : 0;
        ushort4 v = *(const ushort4*)(vfb + (size_t)sc * 96 + c4 * 4);
        a0 += w * bf2f(v.x);
        a1 += w * bf2f(v.y);
        a2 += w * bf2f(v.z);
        a3 += w * bf2f(v.w);
    }
    *(float4*)(out + (size_t)r * 96 + c4 * 4) = make_float4(a0, a1, a2, a3);
}

// ---------------------------------------------------------------------------
extern "C" void kernel_launch(void* const* d_in, const int* in_sizes, int n_in,
                              void* d_out, int out_size, void* d_ws, size_t ws_size,
                              hipStream_t stream) {
    const float* x      = (const float*)d_in[0];
    const float* coords = (const float*)d_in[1];
    const float* Wq1 = (const float*)d_in[2];
    const float* gq1 = (const float*)d_in[3];
    const float* bq1 = (const float*)d_in[4];
    const float* Wq2 = (const float*)d_in[5];
    const float* gq2 = (const float*)d_in[6];
    const float* bq2 = (const float*)d_in[7];
    const float* Wv  = (const float*)d_in[8];
    const float* gv  = (const float*)d_in[9];
    const float* bv  = (const float*)d_in[10];
    const float* Wp1 = (const float*)d_in[11];
    const float* gp1 = (const float*)d_in[12];
    const float* bp1 = (const float*)d_in[13];
    const float* Wp2 = (const float*)d_in[14];
    const float* gp2 = (const float*)d_in[15];
    const float* bp2 = (const float*)d_in[16];
    const float* W1  = (const float*)d_in[17];
    const float* b1  = (const float*)d_in[18];
    const float* W2  = (const float*)d_in[19];
    const float* b2  = (const float*)d_in[20];
    const float* g_out = (const float*)d_in[21];
    const float* b_out = (const float*)d_in[22];
    const int* kmaps = (const int*)d_in[23];
    float* out = (float*)d_out;

    // ---- workspace map (peak 86.0 MB; overlays annotated) ----
    char* ws = (char*)d_ws;
    int*   srcOf  = (int*)ws;                        //  0         + 17,200,000 (live all)
    float* rowAbs = (float*)(ws + 17200000);         //            +    400,000 (live -> attn)
    float* stats  = (float*)(ws + 17600000);         //            +      4,608 (live all)
    u16*   Wq1p   = (u16*)(ws + 17604608);           //            +    552,960
    u16*   Wvp    = (u16*)(ws + 18157568);           //            +    552,960
    u16*   Wq2t   = (u16*)(ws + 18710528);           //            +     82,944
    u16*   w1b    = (u16*)(ws + 18793472);           //            +      6,144
    u16*   w2b    = (u16*)(ws + 18799616);           //            +      3,072  -> 18,802,688
    u16*   xb     = (u16*)(ws + 18802688);           // pad128     + 25,600,000 (-> conv96)
    u16*   bufQb  = (u16*)(ws + 44402688);           //            + 19,200,000 (-> bnapply<0>)
    u16*   bufVb  = (u16*)(ws + 63602688);           //            + 19,200,000 (-> bnapply<1>)
    u16*   bufAb  = (u16*)(ws + 18802688);           // pad128, overlays dead xb      (-> conv4)
    float* pescr  = (float*)(ws + 18802688);         // overlays dead xb/bufAb+bufQb  (-> pe2)
    u16*   vfb    = (u16*)(ws + 18802688);           // overlays dead pescr           (-> gather)
    u16*   wbuf   = (u16*)(ws + 38002688);           // overlays dead pescr-tail/bufQb/bufVb
    float* qf     = (float*)(ws + 82802688);         //            +  1,600,000 (-> attn)
    float* peb    = (float*)(ws + 84402688);         //            +  1,600,000 (-> bnapply<1>)

    hipMemsetAsync(srcOf, 0xFF, (size_t)K_ * N_ * 4, stream);  // -1
    hipMemsetAsync(stats, 0, 6 * 192 * 4, stream);

    k_build_srcof<<<(K_ * M_ + 255) / 256, 256, 0, stream>>>(kmaps, srcOf);
    k_rowabs_cvt<<<N_ / 4, 256, 0, stream>>>(x, rowAbs, xb);
    k_wt96p<<<(KC_ * 9216 + 255) / 256, 256, 0, stream>>>(Wq1, Wq1p);
    k_wt96p<<<(KC_ * 9216 + 255) / 256, 256, 0, stream>>>(Wv, Wvp);
    k_wt4<<<(KC_ * 1536 + 255) / 256, 256, 0, stream>>>(Wq2, Wq2t);
    k_w12b<<<12, 256, 0, stream>>>(W1, W2, w1b, w2b);

    const int cbD  = (N_ + 191) / 192;   // 521
    const int cb4  = (N_ + 127) / 128;   // 782
    const int eb96 = N_ * 96 / 256;      // 37500
    const int eb4  = (N_ * 4 + 255) / 256;

    // both convs + their BN stats in one pass
    k_conv96_dual<<<cbD, 384, 0, stream>>>(xb, Wq1p, Wvp, srcOf, bufQb, bufVb,
                                           stats + 0 * 192, stats + 4 * 192);

    // q-branch: bn+relu -> conv4 -> bn   (bufAb emitted line-aligned, stride 128)
    k_bnapply96_b2b<0, 128><<<eb96, 256, 0, stream>>>(bufQb, stats + 0 * 192, gq1, bq1, nullptr, bufAb);
    k_conv4_mfma<<<cb4, 256, 0, stream>>>(bufAb, Wq2t, srcOf, qf);
    k_bnstats4<<<512, 256, 0, stream>>>(qf, stats + 1 * 192);
    k_bnapply<4, 0><<<eb4, 256, 0, stream>>>(qf, stats + 1 * 192, gq2, bq2, nullptr);

    // pe chain (pescr overlays xb/bufAb + bufQb, all dead by now)
    k_pe1<<<eb96, 256, 0, stream>>>(coords, Wp1, pescr);
    k_bnstats96<<<512, 192, 0, stream>>>(pescr, stats + 2 * 192);
    k_bnapply<96, 0><<<eb96, 256, 0, stream>>>(pescr, stats + 2 * 192, gp1, bp1, nullptr);
    k_pe2<<<eb4, 256, 0, stream>>>(pescr, Wp2, peb);
    k_bnstats4<<<512, 256, 0, stream>>>(peb, stats + 3 * 192);
    k_bnapply<4, 0><<<eb4, 256, 0, stream>>>(peb, stats + 3 * 192, gp2, bp2, nullptr);

    // v-branch: bn+relu+pe -> vfb (bf16, stride 96; overlays dead pescr)
    k_bnapply96_b2b<1, 96><<<eb96, 256, 0, stream>>>(bufVb, stats + 4 * 192, gv, bv, peb, vfb);

    // attention
    k_attn_logits_mfma<<<N_ / 32, 256, 0, stream>>>(qf, srcOf, rowAbs, w1b, b1, w2b, b2, wbuf);
    k_attn_gather<<<(N_ * 24) / 256, 256, 0, stream>>>(vfb, wbuf, srcOf, out);

    // out = relu(bn(out)) + x
    k_bnstats96<<<512, 192, 0, stream>>>(out, stats + 5 * 192);
    k_bnapply<96, 2><<<eb96, 256, 0, stream>>>(out, stats + 5 * 192, g_out, b_out, x);
}

// Round 2
// 1013.722 us; speedup vs baseline: 1.1664x; 1.1664x over previous
//
#include <hip/hip_runtime.h>
#include <math.h>

#define N_  100000
#define P_  96
#define V_  4
#define M_  70000
#define K_  43
#define KC_ 27

typedef unsigned short u16;
typedef __attribute__((ext_vector_type(8))) short bf16x8;
typedef __attribute__((ext_vector_type(4))) float f32x4;
typedef __attribute__((ext_vector_type(16))) float f32x16;

__device__ __forceinline__ u16 f2bf(float f) {
    unsigned int u = __float_as_uint(f);
    u += 0x7fffu + ((u >> 16) & 1u);   // round-to-nearest-even
    return (u16)(u >> 16);
}
__device__ __forceinline__ float bf2f(u16 h) {
    return __uint_as_float(((unsigned int)h) << 16);
}

// async global->LDS DMA, 16 B per lane; dest = wave-uniform base + lane*16
__device__ __forceinline__ void gl_lds16(const u16* g, u16* l) {
    __builtin_amdgcn_global_load_lds(
        (const __attribute__((address_space(1))) void*)g,
        (__attribute__((address_space(3))) void*)l, 16, 0, 0);
}

// ---------------------------------------------------------------------------
__global__ __launch_bounds__(256) void k_build_srcof(const int* __restrict__ km,
                                                     int* __restrict__ srcOf) {
    int idx = blockIdx.x * 256 + threadIdx.x;
    if (idx >= K_ * M_) return;
    int k = idx / M_;
    int e = idx - k * M_;
    const int* p = km + (size_t)(k * M_ + e) * 2;
    srcOf[(size_t)k * N_ + p[1]] = p[0];
}

// rowAbs[r] = sum_j |x[r][j]|  AND  xb = bf16(x), stride 96 (proven layout)
__global__ __launch_bounds__(256) void k_rowabs_cvt(const float* __restrict__ x,
                                                    float* __restrict__ rowAbs,
                                                    u16* __restrict__ xb) {
    int row = blockIdx.x * 4 + (threadIdx.x >> 6);
    int lane = threadIdx.x & 63;
    if (row >= N_) return;
    const float* xr = x + (size_t)row * 96;
    float s = 0.f;
    for (int j = lane; j < 96; j += 64) {
        float v = xr[j];
        s += fabsf(v);
        xb[(size_t)row * 96 + j] = f2bf(v);
    }
#pragma unroll
    for (int o = 32; o > 0; o >>= 1) s += __shfl_down(s, o, 64);
    if (lane == 0) rowAbs[row] = s;
}

// Padded weight image for async staging: Wp[k*10240 + n*104 + j] = bf16(W[k][j][n])
__global__ __launch_bounds__(256) void k_wt96p(const float* __restrict__ W,
                                               u16* __restrict__ Wp) {
    int idx = blockIdx.x * 256 + threadIdx.x;
    if (idx >= KC_ * 96 * 96) return;
    int k = idx / 9216, rem = idx - k * 9216, n = rem / 96, j = rem - n * 96;
    Wp[(size_t)k * 10240 + n * 104 + j] = f2bf(W[(size_t)k * 9216 + j * 96 + n]);
}

// Wt4[k][n][j] = bf16(W[k][j][n]) for n<4 else 0   (27 x 16 x 96)
__global__ __launch_bounds__(256) void k_wt4(const float* __restrict__ W,
                                             u16* __restrict__ Wt) {
    int idx = blockIdx.x * 256 + threadIdx.x;
    if (idx >= KC_ * 16 * 96) return;
    int k = idx / 1536, rem = idx - k * 1536, n = rem / 96, j = rem - n * 96;
    Wt[idx] = (n < 4) ? f2bf(W[(size_t)k * 384 + j * 4 + n]) : (u16)0;
}

// w1b[j][c32] = bf16(W1[c][j]) c<4 else 0; w2b[n16][j] = bf16(W2[j][n]) n<4 else 0
__global__ __launch_bounds__(256) void k_w12b(const float* __restrict__ W1,
                                              const float* __restrict__ W2,
                                              u16* __restrict__ w1b,
                                              u16* __restrict__ w2b) {
    int t = blockIdx.x * 256 + threadIdx.x;
    if (t < 96 * 32) {
        int j = t >> 5, c = t & 31;
        w1b[t] = (c < 4) ? f2bf(W1[c * 96 + j]) : (u16)0;
    }
    if (t < 16 * 96) {
        int n = t / 96, j = t - n * 96;
        w2b[t] = (n < 4) ? f2bf(W2[j * 4 + n]) : (u16)0;
    }
}

// ---------------------------------------------------------------------------
// Dual conv, 32x32x16 MFMA, 192 rows/block, 384 threads (6 waves).
// SW-pipelined gather: loads for step k+1 issued into registers right after
// the mid-step barrier, hidden under step k's MFMA phase; registers are
// ds_written at the top of step k+1. Top-of-loop barrier is raw
// lgkmcnt-only (a __syncthreads there would drain the in-flight prefetch).
// B staged async via global_load_lds; BN stats fused in epilogue.
__global__ __launch_bounds__(384, 3) void k_conv96_dual(
    const u16* __restrict__ xb, const u16* __restrict__ Wqp,
    const u16* __restrict__ Wvp, const int* __restrict__ srcOf,
    u16* __restrict__ yQ, u16* __restrict__ yV,
    float* __restrict__ statsQ, float* __restrict__ statsV) {
    __shared__ u16 sA[192 * 104];   // 39,936 B
    __shared__ u16 sBq[10240];      // 20,480 B (96x104 padded image)
    __shared__ u16 sBv[10240];      // 20,480 B
    const int r0 = blockIdx.x * 192;
    const int t = threadIdx.x;
    const int wv = t / 64, lane = t & 63;
    const int n32 = lane & 31, half = lane >> 5;
    const int ea = t >> 1, jca = (t & 1) * 6;
    const int r = r0 + ea;
    const bool rv = (r < N_);
    f32x16 accq[3], accv[3];
#pragma unroll
    for (int i = 0; i < 3; i++) {
#pragma unroll
        for (int j = 0; j < 16; j++) { accq[i][j] = 0.f; accv[i][j] = 0.f; }
    }

    // --- prologue: gather k=0 into regs, prefetch srcOf[1]
    uint4 va[6];
    int sNext;
    {
        int s0 = rv ? srcOf[r] : -1;
#pragma unroll
        for (int i = 0; i < 6; i++) va[i] = make_uint4(0, 0, 0, 0);
        if (s0 >= 0) {
            const uint4* sp = (const uint4*)(xb + (size_t)s0 * 96);
#pragma unroll
            for (int i = 0; i < 6; i++) va[i] = sp[jca + i];
        }
        sNext = rv ? srcOf[(size_t)N_ + r] : -1;
    }

    for (int k = 0; k < KC_; k++) {
        // (a) raw barrier: all waves done reading sA/sB; keep vmcnt alive
        asm volatile("s_waitcnt lgkmcnt(0)" ::: "memory");
        __builtin_amdgcn_s_barrier();
        __builtin_amdgcn_sched_barrier(0);
        // --- B: async DMA, 40 wave-issues of 1 KB split across 6 waves
        {
            const u16* gq = Wqp + (size_t)k * 10240;
            const u16* gv = Wvp + (size_t)k * 10240;
            for (int i = wv; i < 40; i += 6) {
                int mv = (i >= 20);
                int off = (mv ? i - 20 : i) * 512 + lane * 8;
                gl_lds16((mv ? gv : gq) + off, (mv ? (u16*)sBv : (u16*)sBq) + off);
            }
        }
        // --- A: write prefetched regs (compiler inserts counted vmcnt wait)
#pragma unroll
        for (int i = 0; i < 6; i++)
            *(uint4*)(sA + ea * 104 + (jca + i) * 8) = va[i];
        __syncthreads();   // (b) drains DMA (vmcnt) + ds_writes (lgkm)
        // --- prefetch gather for k+1; issue srcOf[k+2] (slice k+2<=27 valid)
        int sCur = sNext;
        if (k + 1 < KC_) {
            sNext = rv ? srcOf[(size_t)(k + 2) * N_ + r] : -1;
#pragma unroll
            for (int i = 0; i < 6; i++) va[i] = make_uint4(0, 0, 0, 0);
            if (sCur >= 0) {
                const uint4* sp = (const uint4*)(xb + (size_t)sCur * 96);
#pragma unroll
                for (int i = 0; i < 6; i++) va[i] = sp[jca + i];
            }
        }
        __builtin_amdgcn_sched_barrier(0);
        // --- MFMA: 6 K-steps x 3 n-tiles x 2 matrices (hides prefetch latency)
#pragma unroll
        for (int ks = 0; ks < 6; ks++) {
            bf16x8 af = *(const bf16x8*)(sA + (wv * 32 + n32) * 104 + ks * 16 + half * 8);
#pragma unroll
            for (int nt = 0; nt < 3; nt++) {
                bf16x8 bq = *(const bf16x8*)(sBq + (nt * 32 + n32) * 104 + ks * 16 + half * 8);
                accq[nt] = __builtin_amdgcn_mfma_f32_32x32x16_bf16(af, bq, accq[nt], 0, 0, 0);
                bf16x8 bv = *(const bf16x8*)(sBv + (nt * 32 + n32) * 104 + ks * 16 + half * 8);
                accv[nt] = __builtin_amdgcn_mfma_f32_32x32x16_bf16(af, bv, accv[nt], 0, 0, 0);
            }
        }
    }
    // --- outputs (bf16); C/D: col=lane&31, row=(reg&3)+8*(reg>>2)+4*half
#pragma unroll
    for (int nt = 0; nt < 3; nt++) {
#pragma unroll
        for (int reg = 0; reg < 16; reg++) {
            int row = (reg & 3) + 8 * (reg >> 2) + 4 * half;
            int rr = r0 + wv * 32 + row;
            if (rr < N_) {
                yQ[(size_t)rr * 96 + nt * 32 + n32] = f2bf(accq[nt][reg]);
                yV[(size_t)rr * 96 + nt * 32 + n32] = f2bf(accv[nt][reg]);
            }
        }
    }
    // --- fused BN stats (invalid rows contribute exact zeros)
    __syncthreads();
    float* sred = (float*)sA;   // 6 waves x 192 floats
    for (int pass = 0; pass < 2; pass++) {
        f32x16* acc = pass ? accv : accq;
        float* st = pass ? statsV : statsQ;
#pragma unroll
        for (int nt = 0; nt < 3; nt++) {
            float sv = 0.f, qv = 0.f;
#pragma unroll
            for (int reg = 0; reg < 16; reg++) {
                float a = acc[nt][reg];
                sv += a; qv += a * a;
            }
            sv += __shfl_xor(sv, 32, 64);
            qv += __shfl_xor(qv, 32, 64);
            if (half == 0) {
                sred[wv * 192 + nt * 32 + n32] = sv;
                sred[wv * 192 + 96 + nt * 32 + n32] = qv;
            }
        }
        __syncthreads();
        if (t < 192) {
            float tot = 0.f;
#pragma unroll
            for (int w = 0; w < 6; w++) tot += sred[w * 192 + t];
            atomicAdd(&st[t], tot);
        }
        __syncthreads();
    }
}

// 96->4 conv via MFMA (N padded to 16). 128 rows/block; same SW pipeline.
__global__ __launch_bounds__(256) void k_conv4_mfma(
    const u16* __restrict__ xbA, const u16* __restrict__ Wt4,
    const int* __restrict__ srcOf, float* __restrict__ qf) {
    __shared__ u16 sA[128 * 104];
    __shared__ u16 sB[16 * 104];
    const int r0 = blockIdx.x * 128;
    const int t = threadIdx.x;
    const int wv = t >> 6, lane = t & 63;
    const int m = lane & 15, quad = lane >> 4;
    const int ea = t >> 1, jca = (t & 1) * 6;
    const int r = r0 + ea;
    const bool rv = (r < N_);
    f32x4 acc[2];
    acc[0] = (f32x4){0.f, 0.f, 0.f, 0.f};
    acc[1] = (f32x4){0.f, 0.f, 0.f, 0.f};

    uint4 va[6];
    int sNext;
    {
        int s0 = rv ? srcOf[r] : -1;
#pragma unroll
        for (int i = 0; i < 6; i++) va[i] = make_uint4(0, 0, 0, 0);
        if (s0 >= 0) {
            const uint4* sp = (const uint4*)(xbA + (size_t)s0 * 96);
#pragma unroll
            for (int i = 0; i < 6; i++) va[i] = sp[jca + i];
        }
        sNext = rv ? srcOf[(size_t)N_ + r] : -1;
    }

    for (int k = 0; k < KC_; k++) {
        asm volatile("s_waitcnt lgkmcnt(0)" ::: "memory");
        __builtin_amdgcn_s_barrier();
        __builtin_amdgcn_sched_barrier(0);
        if (t < 192) {
            int n = t / 12, jc = t - (t / 12) * 12;
            *(uint4*)(sB + n * 104 + jc * 8) =
                *(const uint4*)(Wt4 + (size_t)k * 1536 + n * 96 + jc * 8);
        }
#pragma unroll
        for (int i = 0; i < 6; i++)
            *(uint4*)(sA + ea * 104 + (jca + i) * 8) = va[i];
        __syncthreads();
        int sCur = sNext;
        if (k + 1 < KC_) {
            sNext = rv ? srcOf[(size_t)(k + 2) * N_ + r] : -1;
#pragma unroll
            for (int i = 0; i < 6; i++) va[i] = make_uint4(0, 0, 0, 0);
            if (sCur >= 0) {
                const uint4* sp = (const uint4*)(xbA + (size_t)sCur * 96);
#pragma unroll
                for (int i = 0; i < 6; i++) va[i] = sp[jca + i];
            }
        }
        __builtin_amdgcn_sched_barrier(0);
#pragma unroll
        for (int kk = 0; kk < 3; kk++) {
            bf16x8 bfr = *(const bf16x8*)(sB + m * 104 + kk * 32 + quad * 8);
#pragma unroll
            for (int rt = 0; rt < 2; rt++) {
                bf16x8 af = *(const bf16x8*)(sA + ((wv * 2 + rt) * 16 + m) * 104 + kk * 32 + quad * 8);
                acc[rt] = __builtin_amdgcn_mfma_f32_16x16x32_bf16(af, bfr, acc[rt], 0, 0, 0);
            }
        }
    }
    if (m < 4) {
#pragma unroll
        for (int rt = 0; rt < 2; rt++)
#pragma unroll
            for (int rg = 0; rg < 4; rg++) {
                int rr = r0 + (wv * 2 + rt) * 16 + quad * 4 + rg;
                if (rr < N_) qf[(size_t)rr * 4 + m] = acc[rt][rg];
            }
    }
}

// ---------------------------------------------------------------------------
__global__ __launch_bounds__(192) void k_bnstats96(const float* __restrict__ xin,
                                                   float* __restrict__ stats) {
    __shared__ float sS[192], sQ[192];
    int t = threadIdx.x;
    int ch = t % 96, half = t / 96;
    float s = 0.f, q = 0.f;
    for (int r = blockIdx.x * 2 + half; r < N_; r += gridDim.x * 2) {
        float v = xin[(size_t)r * 96 + ch];
        s += v; q += v * v;
    }
    sS[t] = s; sQ[t] = q;
    __syncthreads();
    if (t < 96) {
        atomicAdd(&stats[ch], sS[t] + sS[t + 96]);
        atomicAdd(&stats[96 + ch], sQ[t] + sQ[t + 96]);
    }
}

__global__ __launch_bounds__(256) void k_bnstats4(const float* __restrict__ xin,
                                                  float* __restrict__ stats) {
    __shared__ float sS[256], sQ[256];
    int t = threadIdx.x;
    int c = t & 3, sub = t >> 2;
    float s = 0.f, q = 0.f;
    for (int r = blockIdx.x * 64 + sub; r < N_; r += gridDim.x * 64) {
        float v = xin[(size_t)r * 4 + c];
        s += v; q += v * v;
    }
    sS[t] = s; sQ[t] = q;
    __syncthreads();
    for (int off = 128; off >= 4; off >>= 1) {
        if (t < off) { sS[t] += sS[t + off]; sQ[t] += sQ[t + off]; }
        __syncthreads();
    }
    if (t < 4) {
        atomicAdd(&stats[t], sS[t]);
        atomicAdd(&stats[96 + t], sQ[t]);
    }
}

// f32 in/out (MODE 0: relu(bn)  MODE 2: relu(bn)+aux)
template <int C, int MODE>
__global__ __launch_bounds__(256) void k_bnapply(float* __restrict__ y,
                                                 const float* __restrict__ stats,
                                                 const float* __restrict__ g,
                                                 const float* __restrict__ b,
                                                 const float* __restrict__ aux) {
    int idx = blockIdx.x * 256 + threadIdx.x;
    if (idx >= N_ * C) return;
    int ch = idx % C;
    float mean = stats[ch] * (1.f / N_);
    float var = stats[96 + ch] * (1.f / N_) - mean * mean;
    float scale = g[ch] * rsqrtf(fmaxf(var, 0.f) + 1e-5f);
    float v = (y[idx] - mean) * scale + b[ch];
    v = fmaxf(v, 0.f);
    if (MODE == 2) v += aux[idx];
    y[idx] = v;
}

// bf16 in -> bf16 out, C=96. MODE 0: relu(bn)  MODE 1: relu(bn)+pe_repeat
template <int MODE>
__global__ __launch_bounds__(256) void k_bnapply96_b2b(
    const u16* __restrict__ yin, const float* __restrict__ stats,
    const float* __restrict__ g, const float* __restrict__ b,
    const float* __restrict__ aux, u16* __restrict__ yout) {
    int idx = blockIdx.x * 256 + threadIdx.x;
    if (idx >= N_ * 96) return;
    int ch = idx % 96;
    float mean = stats[ch] * (1.f / N_);
    float var = stats[96 + ch] * (1.f / N_) - mean * mean;
    float scale = g[ch] * rsqrtf(fmaxf(var, 0.f) + 1e-5f);
    float v = (bf2f(yin[idx]) - mean) * scale + b[ch];
    v = fmaxf(v, 0.f);
    if (MODE == 1) { int r = idx / 96; v += aux[(size_t)r * 4 + (ch / 24)]; }
    yout[idx] = f2bf(v);
}

__global__ __launch_bounds__(256) void k_pe1(const float* __restrict__ coords,
                                             const float* __restrict__ Wp1,
                                             float* __restrict__ out) {
    int idx = blockIdx.x * 256 + threadIdx.x;
    if (idx >= N_ * 96) return;
    int r = idx / 96, ch = idx - r * 96;
    float c0 = coords[r * 3], c1 = coords[r * 3 + 1], c2 = coords[r * 3 + 2];
    out[idx] = c0 * Wp1[ch] + c1 * Wp1[96 + ch] + c2 * Wp1[192 + ch];
}

__global__ __launch_bounds__(256) void k_pe2(const float* __restrict__ hin,
                                             const float* __restrict__ Wp2,
                                             float* __restrict__ out) {
    int idx = blockIdx.x * 256 + threadIdx.x;
    if (idx >= N_ * 4) return;
    int r = idx / 4, c = idx & 3;
    const float* hr = hin + (size_t)r * 96;
    float acc = 0.f;
#pragma unroll 4
    for (int j = 0; j < 96; j++) acc += hr[j] * Wp2[j * 4 + c];
    out[idx] = acc;
}

// ---------------------------------------------------------------------------
// MFMA attention logits (32 rows/block), bf16 LDS softmax state.
__global__ __launch_bounds__(256) void k_attn_logits_mfma(
    const float* __restrict__ qf, const int* __restrict__ srcOf,
    const float* __restrict__ rowAbs,
    const u16* __restrict__ w1b, const float* __restrict__ b1,
    const u16* __restrict__ w2b, const float* __restrict__ b2,
    u16* __restrict__ wb) {
    __shared__ u16 hbuf[4][16 * 104];
    __shared__ u16 slogb[32][176];
    __shared__ u16 smk16[32][44];
    const int t = threadIdx.x;
    const int wv = t >> 6, lane = t & 63;
    const int col = lane & 15, quad = lane >> 4;
    const int r0 = blockIdx.x * 32;

    bf16x8 w1f[6];
    float b1v[6];
#pragma unroll
    for (int nt = 0; nt < 6; nt++) {
        w1f[nt] = *(const bf16x8*)(w1b + (nt * 16 + col) * 32 + quad * 8);
        b1v[nt] = b1[nt * 16 + col];
    }
    bf16x8 w2f[3];
#pragma unroll
    for (int kk = 0; kk < 3; kk++)
        w2f[kk] = *(const bf16x8*)(w2b + col * 96 + kk * 32 + quad * 8);
    float b2v = b2[col & 3];

    u16* hb = hbuf[wv];
    for (int tt = 0; tt < 22; tt++) {
        int tileBase = (wv * 22 + tt) * 16;
        bf16x8 af = (bf16x8){0, 0, 0, 0, 0, 0, 0, 0};
        if (quad == 0) {
            int P = tileBase + col;
            int rL = P / 44, k = P - rL * 44;
            int kc = (k < 43) ? k : 42;
            int r = r0 + rL;
            int s = srcOf[(size_t)kc * N_ + r];
            if (k == 43) s = -1;
            int sc = (s >= 0) ? s : 0;
            float mk = (s >= 0 && rowAbs[sc] > 0.f) ? 1.f : 0.f;
            float4 qs = *(const float4*)(qf + (size_t)sc * 4);
            float4 qr = *(const float4*)(qf + (size_t)r * 4);
            af[0] = (short)f2bf((qs.x - qr.x) * mk);
            af[1] = (short)f2bf((qs.y - qr.y) * mk);
            af[2] = (short)f2bf((qs.z - qr.z) * mk);
            af[3] = (short)f2bf((qs.w - qr.w) * mk);
            if (k < 43) smk16[rL][k] = (u16)(mk > 0.f ? 1 : 0);
        }
        f32x4 c1[6];
#pragma unroll
        for (int nt = 0; nt < 6; nt++) {
            c1[nt] = (f32x4){0.f, 0.f, 0.f, 0.f};
            c1[nt] = __builtin_amdgcn_mfma_f32_16x16x32_bf16(af, w1f[nt], c1[nt], 0, 0, 0);
        }
#pragma unroll
        for (int nt = 0; nt < 6; nt++) {
#pragma unroll
            for (int rg = 0; rg < 4; rg++) {
                float h = fmaxf(c1[nt][rg] + b1v[nt], 0.f);
                hb[(quad * 4 + rg) * 104 + nt * 16 + col] = f2bf(h);
            }
        }
        f32x4 acc2 = (f32x4){0.f, 0.f, 0.f, 0.f};
#pragma unroll
        for (int kk = 0; kk < 3; kk++) {
            bf16x8 a2 = *(const bf16x8*)(hb + col * 104 + kk * 32 + quad * 8);
            acc2 = __builtin_amdgcn_mfma_f32_16x16x32_bf16(a2, w2f[kk], acc2, 0, 0, 0);
        }
        if (col < 4) {
#pragma unroll
            for (int rg = 0; rg < 4; rg++) {
                int P = tileBase + quad * 4 + rg;
                int rL = P / 44, k = P - rL * 44;
                if (k < 43) {
                    float mval = (float)smk16[rL][k];
                    slogb[rL][k * 4 + col] = f2bf((acc2[rg] + b2v) * mval);
                }
            }
        }
    }
    __syncthreads();

    if (t < 128) {
        int rL = t >> 2, c = t & 3;
        float mx = 0.f;
        for (int k = 0; k < K_; k++) mx = fmaxf(mx, bf2f(slogb[rL][k * 4 + c]));
        float den = 0.f;
        for (int k = 0; k < K_; k++) den += __expf(bf2f(slogb[rL][k * 4 + c]) - mx);
        float inv = 1.f / den;
        for (int k = 0; k < K_; k++)
            slogb[rL][k * 4 + c] = f2bf(__expf(bf2f(slogb[rL][k * 4 + c]) - mx) * inv);
    }
    __syncthreads();

    for (int p = t; p < 32 * 43; p += 256) {
        int rL = p / 43, k = p - rL * 43;
        int idxk = (k < 27) ? k : ((k < 35) ? (k - 27) : (k - 35));
        u16 mk = smk16[rL][k];
        ushort4 wout = make_ushort4(0, 0, 0, 0);
        if (mk) {
            wout.x = slogb[rL][idxk * 4 + 0];
            wout.y = slogb[rL][idxk * 4 + 1];
            wout.z = slogb[rL][idxk * 4 + 2];
            wout.w = slogb[rL][idxk * 4 + 3];
        }
        *(ushort4*)(wb + ((size_t)(r0 + rL) * 44 + k) * 4) = wout;
    }
}

// out[r][ch] = sum_k wb[r][k][cg] * vfb[src_k[r]][ch]
__global__ __launch_bounds__(256) void k_attn_gather(
    const u16* __restrict__ vfb, const u16* __restrict__ wb,
    const int* __restrict__ srcOf, float* __restrict__ out) {
    int idx = blockIdx.x * 256 + threadIdx.x;
    int r = idx / 24, c4 = idx - r * 24;
    if (r >= N_) return;
    int cg = c4 / 6;
    const u16* wrow = wb + (size_t)r * 176 + cg;
    float a0 = 0.f, a1 = 0.f, a2 = 0.f, a3 = 0.f;
    for (int k = 0; k < K_; k++) {
        int s = srcOf[(size_t)k * N_ + r];
        float w = bf2f(wrow[(size_t)k * 4]);
        w = (s >= 0) ? w : 0.f;
        int sc = (s >= 0) ? s : 0;
        ushort4 v = *(const ushort4*)(vfb + (size_t)sc * 96 + c4 * 4);
        a0 += w * bf2f(v.x);
        a1 += w * bf2f(v.y);
        a2 += w * bf2f(v.z);
        a3 += w * bf2f(v.w);
    }
    *(float4*)(out + (size_t)r * 96 + c4 * 4) = make_float4(a0, a1, a2, a3);
}

// ---------------------------------------------------------------------------
extern "C" void kernel_launch(void* const* d_in, const int* in_sizes, int n_in,
                              void* d_out, int out_size, void* d_ws, size_t ws_size,
                              hipStream_t stream) {
    const float* x      = (const float*)d_in[0];
    const float* coords = (const float*)d_in[1];
    const float* Wq1 = (const float*)d_in[2];
    const float* gq1 = (const float*)d_in[3];
    const float* bq1 = (const float*)d_in[4];
    const float* Wq2 = (const float*)d_in[5];
    const float* gq2 = (const float*)d_in[6];
    const float* bq2 = (const float*)d_in[7];
    const float* Wv  = (const float*)d_in[8];
    const float* gv  = (const float*)d_in[9];
    const float* bv  = (const float*)d_in[10];
    const float* Wp1 = (const float*)d_in[11];
    const float* gp1 = (const float*)d_in[12];
    const float* bp1 = (const float*)d_in[13];
    const float* Wp2 = (const float*)d_in[14];
    const float* gp2 = (const float*)d_in[15];
    const float* bp2 = (const float*)d_in[16];
    const float* W1  = (const float*)d_in[17];
    const float* b1  = (const float*)d_in[18];
    const float* W2  = (const float*)d_in[19];
    const float* b2  = (const float*)d_in[20];
    const float* g_out = (const float*)d_in[21];
    const float* b_out = (const float*)d_in[22];
    const int* kmaps = (const int*)d_in[23];
    float* out = (float*)d_out;

    // ---- workspace map (round-0 proven layout) ----
    char* ws = (char*)d_ws;
    int*   srcOf  = (int*)ws;                        //  0        + 17,200,000
    float* rowAbs = (float*)(ws + 17200000);         //           +    400,000
    u16*   xb     = (u16*)(ws + 17600000);           //           + 19,200,000
    u16*   bufQb  = (u16*)(ws + 36800000);           //           + 19,200,000
    u16*   bufVb  = (u16*)(ws + 56000000);           //           + 19,200,000
    u16*   bufAb  = (u16*)(ws + 75200000);           //           + 19,200,000
    u16*   vfb    = (u16*)(ws + 75200000);           // overlays bufAb (dead after conv4)
    float* pescr  = (float*)(ws + 17600000);         // overlays xb+bufQb (dead by pe1)
    u16*   wbuf   = (u16*)(ws + 17600000);           // overlays pescr (dead after pe2)
    float* qf     = (float*)(ws + 94400000);         //           +  1,600,000
    float* peb    = (float*)(ws + 96000000);         //           +  1,600,000
    u16*   Wq1p   = (u16*)(ws + 97600000);           //           +    552,960
    u16*   Wvp    = (u16*)(ws + 98152960);           //           +    552,960
    u16*   Wq2t   = (u16*)(ws + 98705920);           //           +     82,944
    u16*   w1b    = (u16*)(ws + 98788864);           //           +      6,144
    u16*   w2b    = (u16*)(ws + 98795008);           //           +      3,072
    float* stats  = (float*)(ws + 98798080);         //           +      4,608

    hipMemsetAsync(srcOf, 0xFF, (size_t)K_ * N_ * 4, stream);  // -1
    hipMemsetAsync(stats, 0, 6 * 192 * 4, stream);

    k_build_srcof<<<(K_ * M_ + 255) / 256, 256, 0, stream>>>(kmaps, srcOf);
    k_rowabs_cvt<<<N_ / 4, 256, 0, stream>>>(x, rowAbs, xb);
    k_wt96p<<<(KC_ * 9216 + 255) / 256, 256, 0, stream>>>(Wq1, Wq1p);
    k_wt96p<<<(KC_ * 9216 + 255) / 256, 256, 0, stream>>>(Wv, Wvp);
    k_wt4<<<(KC_ * 1536 + 255) / 256, 256, 0, stream>>>(Wq2, Wq2t);
    k_w12b<<<12, 256, 0, stream>>>(W1, W2, w1b, w2b);

    const int cbD  = (N_ + 191) / 192;   // 521
    const int cb4  = (N_ + 127) / 128;   // 782
    const int eb96 = N_ * 96 / 256;      // 37500
    const int eb4  = (N_ * 4 + 255) / 256;

    // both convs + their BN stats in one pass
    k_conv96_dual<<<cbD, 384, 0, stream>>>(xb, Wq1p, Wvp, srcOf, bufQb, bufVb,
                                           stats + 0 * 192, stats + 4 * 192);

    // q-branch: bn+relu -> conv4 -> bn
    k_bnapply96_b2b<0><<<eb96, 256, 0, stream>>>(bufQb, stats + 0 * 192, gq1, bq1, nullptr, bufAb);
    k_conv4_mfma<<<cb4, 256, 0, stream>>>(bufAb, Wq2t, srcOf, qf);
    k_bnstats4<<<512, 256, 0, stream>>>(qf, stats + 1 * 192);
    k_bnapply<4, 0><<<eb4, 256, 0, stream>>>(qf, stats + 1 * 192, gq2, bq2, nullptr);

    // pe chain (pescr overlays xb+bufQb, both dead by now)
    k_pe1<<<eb96, 256, 0, stream>>>(coords, Wp1, pescr);
    k_bnstats96<<<512, 192, 0, stream>>>(pescr, stats + 2 * 192);
    k_bnapply<96, 0><<<eb96, 256, 0, stream>>>(pescr, stats + 2 * 192, gp1, bp1, nullptr);
    k_pe2<<<eb4, 256, 0, stream>>>(pescr, Wp2, peb);
    k_bnstats4<<<512, 256, 0, stream>>>(peb, stats + 3 * 192);
    k_bnapply<4, 0><<<eb4, 256, 0, stream>>>(peb, stats + 3 * 192, gp2, bp2, nullptr);

    // v-branch: bn+relu+pe -> vfb (bf16; overlays bufAb after conv4)
    k_bnapply96_b2b<1><<<eb96, 256, 0, stream>>>(bufVb, stats + 4 * 192, gv, bv, peb, vfb);

    // attention
    k_attn_logits_mfma<<<N_ / 32, 256, 0, stream>>>(qf, srcOf, rowAbs, w1b, b1, w2b, b2, wbuf);
    k_attn_gather<<<(N_ * 24) / 256, 256, 0, stream>>>(vfb, wbuf, srcOf, out);

    // out = relu(bn(out)) + x
    k_bnstats96<<<512, 192, 0, stream>>>(out, stats + 5 * 192);
    k_bnapply<96, 2><<<eb96, 256, 0, stream>>>(out, stats + 5 * 192, g_out, b_out, x);
}